// Round 1
// baseline (151.625 us; speedup 1.0000x reference)
//
#include <hip/hip_runtime.h>
#include <hip/hip_cooperative_groups.h>
#include <math.h>

namespace cg = cooperative_groups;

// Planck*c in J*m (f32 — matches jnp f32 reference math)
#define HCF 1.98644586e-25f

constexpr int BLOCK = 256;
constexpr int RPT   = 4;                     // rays per thread
constexpr int RAYS_PER_BLOCK = BLOCK * RPT;  // 1024
constexpr int MAXN  = 8192;                  // max rays supported by device-global scratch

// Device-global scratch for per-ray max-dot (uint-encoded f32 >= 0).
// Zeroed in-kernel every launch (phase 0) -> no cross-replay state, no d_ws use.
__device__ unsigned g_maxenc[MAXN];

struct Bmat { float B00,B01,B02,B10,B11,B12,B20,B21,B22; };

// B_lab = rot(angle) @ inv(prim(lattice))^T, f32 — identical math to verified kernel.
__device__ __forceinline__ Bmat make_B(const float* __restrict__ lattice,
                                       const float* __restrict__ angle)
{
    const float a = lattice[0], b = lattice[1], cc = lattice[2];
    const float cal = cosf(lattice[3]), cbe = cosf(lattice[4]);
    const float cga = cosf(lattice[5]), sga = sinf(lattice[5]);
    const float e3y = (cal - cbe * cga) / sga;
    const float e3z = sqrtf(fmaxf(1.0f - cbe * cbe - e3y * e3y, 1e-12f));
    // prim (upper triangular)
    const float p01 = b * cga, p02 = cc * cbe, p11 = b * sga, p12 = cc * e3y, p22 = cc * e3z;
    // analytic inverse of upper-triangular prim; recip = inv(prim)^T (lower tri)
    const float i00 = 1.0f / a, i11 = 1.0f / p11, i22 = 1.0f / p22;
    const float i01 = -p01 * (i00 * i11);                          // recip[1][0]
    const float i12 = -p12 * (i11 * i22);                          // recip[2][1]
    const float i02 = (p01 * p12 - p02 * p11) * (i00 * i11 * i22); // recip[2][0]
    // rot = Rx(t0) @ Ry(t1) @ Rz(t2)
    const float c0 = cosf(angle[0]), s0 = sinf(angle[0]);
    const float c1 = cosf(angle[1]), s1 = sinf(angle[1]);
    const float c2 = cosf(angle[2]), s2 = sinf(angle[2]);
    const float M00 = c1 * c2,                M01 = -c1 * s2,               M02 = s1;
    const float M10 = c0 * s2 + s0 * s1 * c2, M11 = c0 * c2 - s0 * s1 * s2, M12 = -s0 * c1;
    const float M20 = s0 * s2 - c0 * s1 * c2, M21 = s0 * c2 + c0 * s1 * s2, M22 = c0 * c1;
    Bmat r;
    r.B00 = M00 * i00 + M01 * i01 + M02 * i02;
    r.B01 = M01 * i11 + M02 * i12;
    r.B02 = M02 * i22;
    r.B10 = M10 * i00 + M11 * i01 + M12 * i02;
    r.B11 = M11 * i11 + M12 * i12;
    r.B12 = M12 * i22;
    r.B20 = M20 * i00 + M21 * i01 + M22 * i02;
    r.B21 = M21 * i11 + M22 * i12;
    r.B22 = M22 * i22;
    return r;
}

// Phase-1 body: stage one 256-entry theo chunk into LDS (energy-filtered),
// per-thread max-dot over RPT rays, uint-atomicMax into maxenc.
// Copied verbatim (modulo maxenc target) from the harness-verified kernel.
__device__ __forceinline__ void maxdot_body(
    const float* __restrict__ lattice, const float* __restrict__ angle,
    const float* __restrict__ uq_exp,  const int* __restrict__ hkl,
    const float* __restrict__ e_min_p,
    unsigned* __restrict__ maxenc, int n, int m, int nchunks, float4* s_uq)
{
    const int tid   = threadIdx.x;
    const int chunk = blockIdx.x % nchunks;
    const int rg    = blockIdx.x / nchunks;

    const Bmat B = make_B(lattice, angle);

    const int ti = chunk * BLOCK + tid;
    float4 v = make_float4(0.f, 0.f, 0.f, 0.f);
    if (ti < m) {
        const float h0 = (float)hkl[3 * ti + 0];
        const float h1 = (float)hkl[3 * ti + 1];
        const float h2 = (float)hkl[3 * ti + 2];
        const float qx = B.B00 * h0 + B.B01 * h1 + B.B02 * h2;
        const float qy = B.B10 * h0 + B.B11 * h1 + B.B12 * h2;
        const float qz = B.B20 * h0 + B.B21 * h1 + B.B22 * h2;
        const float qn = sqrtf(qx * qx + qy * qy + qz * qz);
        const float inv = 1.0f / qn;
        const float ux = qx * inv, uy = qy * inv, uz = qz * inv;
        const float st = fabsf(uz);
        const float energy = HCF * qn / (2.0f * fmaxf(st, 1e-9f));
        if (energy >= e_min_p[0]) v = make_float4(ux, uy, uz, 0.f);
        // masked -> zero vector: dot = 0 -> phi = pi/2 -> exp underflows to exactly
        // 0.0f, same as reference's phi = pi contribution. Bit-identical result.
    }
    s_uq[tid] = v;
    __syncthreads();

    float rx[RPT], ry[RPT], rz[RPT], mx[RPT];
    bool valid[RPT];
#pragma unroll
    for (int i = 0; i < RPT; ++i) {
        const int ray = rg * RAYS_PER_BLOCK + i * BLOCK + tid;
        valid[i] = (ray < n);
        float x = 0.f, y = 0.f, z = 0.f;
        if (valid[i]) { x = uq_exp[3 * ray]; y = uq_exp[3 * ray + 1]; z = uq_exp[3 * ray + 2]; }
        rx[i] = x; ry[i] = y; rz[i] = z;
        mx[i] = 0.f;  // clamp-at-zero: negative max-dot contributes exactly 0 anyway
    }

#pragma unroll 4
    for (int j = 0; j < BLOCK; ++j) {
        const float4 t = s_uq[j];   // wave-uniform address -> LDS broadcast, no conflict
#pragma unroll
        for (int i = 0; i < RPT; ++i) {
            const float d = rx[i] * t.x + ry[i] * t.y + rz[i] * t.z;
            mx[i] = fmaxf(mx[i], d);
        }
    }

#pragma unroll
    for (int i = 0; i < RPT; ++i) {
        if (valid[i]) {
            const int ray = rg * RAYS_PER_BLOCK + i * BLOCK + tid;
            // mx >= 0 so float ordering == uint ordering on the bit pattern
            atomicMax(&maxenc[ray], __float_as_uint(mx[i]));
        }
    }
}

// Fused cooperative kernel: zero scratch -> grid.sync -> maxdot -> grid.sync
// -> block 0 finalizes and stores the mean. No workspace, no memsets, 1 dispatch.
__global__ __launch_bounds__(BLOCK) void refiner_fused_kernel(
    const float* __restrict__ lattice, const float* __restrict__ angle,
    const float* __restrict__ uq_exp,  const int* __restrict__ hkl,
    const float* __restrict__ phi_max_p, const float* __restrict__ e_min_p,
    float* __restrict__ out, int n, int m, int nchunks)
{
    __shared__ float4 s_uq[BLOCK];
    cg::grid_group grid = cg::this_grid();
    const int tid = threadIdx.x;

    // ---- phase 0: zero the per-ray scratch (grid-strided) ----
    for (int i = blockIdx.x * BLOCK + tid; i < n; i += gridDim.x * BLOCK)
        g_maxenc[i] = 0u;
    grid.sync();

    // ---- phase 1: max-dot with atomicMax into device-global scratch ----
    maxdot_body(lattice, angle, uq_exp, hkl, e_min_p, g_maxenc, n, m, nchunks, s_uq);
    grid.sync();

    // ---- phase 2: block 0 finalizes (5000 acos/exp + block reduction) ----
    if (blockIdx.x == 0) {
        float wsum = 0.f;
        for (int i = tid; i < n; i += BLOCK) {
            float c = __uint_as_float(g_maxenc[i]);
            c = fminf(c, 1.0f - 1e-6f);           // reference's upper clip
            const float phi = acosf(c);
            const float t = phi / phi_max_p[0];
            wsum += expf(-0.5f * t * t);
        }
#pragma unroll
        for (int off = 32; off > 0; off >>= 1) wsum += __shfl_down(wsum, off, 64);
        __shared__ float s[BLOCK / 64];
        const int lane = tid & 63, wv = tid >> 6;
        if (lane == 0) s[wv] = wsum;
        __syncthreads();
        if (tid == 0) {
            float tot = 0.f;
#pragma unroll
            for (int k = 0; k < BLOCK / 64; ++k) tot += s[k];
            out[0] = tot / (float)n;
        }
    }
}

// ---------------- fallback: the harness-verified two-kernel path ----------------
__global__ __launch_bounds__(BLOCK) void refiner_maxdot_kernel(
    const float* __restrict__ lattice, const float* __restrict__ angle,
    const float* __restrict__ uq_exp,  const int* __restrict__ hkl,
    const float* __restrict__ e_min_p,
    unsigned* __restrict__ maxenc, int n, int m, int nchunks)
{
    __shared__ float4 s_uq[BLOCK];
    maxdot_body(lattice, angle, uq_exp, hkl, e_min_p, maxenc, n, m, nchunks, s_uq);
}

__global__ __launch_bounds__(BLOCK) void refiner_finalize_kernel(
    const unsigned* __restrict__ maxenc, const float* __restrict__ phi_max_p,
    float* __restrict__ out, int n)
{
    const int i = blockIdx.x * BLOCK + threadIdx.x;
    float w = 0.f;
    if (i < n) {
        float c = __uint_as_float(maxenc[i]);
        c = fminf(c, 1.0f - 1e-6f);
        const float phi = acosf(c);
        const float t = phi / phi_max_p[0];
        w = expf(-0.5f * t * t);
    }
#pragma unroll
    for (int off = 32; off > 0; off >>= 1) w += __shfl_down(w, off, 64);
    __shared__ float s[BLOCK / 64];
    const int lane = threadIdx.x & 63, wv = threadIdx.x >> 6;
    if (lane == 0) s[wv] = w;
    __syncthreads();
    if (threadIdx.x == 0) {
        float tot = 0.f;
#pragma unroll
        for (int k = 0; k < BLOCK / 64; ++k) tot += s[k];
        atomicAdd(out, tot / (float)n);
    }
}

extern "C" void kernel_launch(void* const* d_in, const int* in_sizes, int n_in,
                              void* d_out, int out_size, void* d_ws, size_t ws_size,
                              hipStream_t stream) {
    const float* lattice = (const float*)d_in[0];
    const float* angle   = (const float*)d_in[1];
    const float* uq_exp  = (const float*)d_in[2];
    const int*   hkl     = (const int*)d_in[3];
    const float* phi_max = (const float*)d_in[4];
    const float* e_min   = (const float*)d_in[5];
    int n = in_sizes[2] / 3;   // ~5000 exp rays
    int m = in_sizes[3] / 3;   // ~12.7k hkl

    int nchunks = (m + BLOCK - 1) / BLOCK;
    int nrg     = (n + RAYS_PER_BLOCK - 1) / RAYS_PER_BLOCK;
    int nblocks = nrg * nchunks;
    float* outp = (float*)d_out;

    // Cooperative path: 250 blocks x 256 thr, ~40 VGPR, 4.1 KB LDS -> trivially
    // co-resident on 256 CUs (cap guard at 1024 blocks = 4 blk/CU floor).
    if (n <= MAXN && nblocks <= 1024) {
        void* args[] = {
            (void*)&lattice, (void*)&angle, (void*)&uq_exp, (void*)&hkl,
            (void*)&phi_max, (void*)&e_min, (void*)&outp,
            (void*)&n, (void*)&m, (void*)&nchunks
        };
        hipError_t err = hipLaunchCooperativeKernel(refiner_fused_kernel,
            dim3(nblocks), dim3(BLOCK), args, 0, stream);
        if (err == hipSuccess) return;
        // fall through to the verified path on any refusal
    }

    unsigned* maxenc = (unsigned*)d_ws;
    hipMemsetAsync(maxenc, 0, (size_t)n * sizeof(unsigned), stream);
    hipMemsetAsync(d_out, 0, sizeof(float), stream);
    refiner_maxdot_kernel<<<dim3(nblocks), dim3(BLOCK), 0, stream>>>(
        lattice, angle, uq_exp, hkl, e_min, maxenc, n, m, nchunks);
    refiner_finalize_kernel<<<dim3((n + BLOCK - 1) / BLOCK), dim3(BLOCK), 0, stream>>>(
        maxenc, phi_max, outp, n);
}

// Round 2
// 93.844 us; speedup vs baseline: 1.6157x; 1.6157x over previous
//
#include <hip/hip_runtime.h>
#include <math.h>

// Planck*c in J*m (f32 — matches jnp f32 reference math)
#define HCF 1.98644586e-25f

constexpr int BLOCK = 256;
constexpr int RPT   = 4;                     // rays per thread
constexpr int RAYS_PER_BLOCK = BLOCK * RPT;  // 1024

struct Bmat { float B00,B01,B02,B10,B11,B12,B20,B21,B22; };

// B_lab = rot(angle) @ inv(prim(lattice))^T, f32 — identical math to verified kernel.
__device__ __forceinline__ Bmat make_B(const float* __restrict__ lattice,
                                       const float* __restrict__ angle)
{
    const float a = lattice[0], b = lattice[1], cc = lattice[2];
    const float cal = cosf(lattice[3]), cbe = cosf(lattice[4]);
    const float cga = cosf(lattice[5]), sga = sinf(lattice[5]);
    const float e3y = (cal - cbe * cga) / sga;
    const float e3z = sqrtf(fmaxf(1.0f - cbe * cbe - e3y * e3y, 1e-12f));
    // prim (upper triangular)
    const float p01 = b * cga, p02 = cc * cbe, p11 = b * sga, p12 = cc * e3y, p22 = cc * e3z;
    // analytic inverse of upper-triangular prim; recip = inv(prim)^T (lower tri)
    const float i00 = 1.0f / a, i11 = 1.0f / p11, i22 = 1.0f / p22;
    const float i01 = -p01 * (i00 * i11);                          // recip[1][0]
    const float i12 = -p12 * (i11 * i22);                          // recip[2][1]
    const float i02 = (p01 * p12 - p02 * p11) * (i00 * i11 * i22); // recip[2][0]
    // rot = Rx(t0) @ Ry(t1) @ Rz(t2)
    const float c0 = cosf(angle[0]), s0 = sinf(angle[0]);
    const float c1 = cosf(angle[1]), s1 = sinf(angle[1]);
    const float c2 = cosf(angle[2]), s2 = sinf(angle[2]);
    const float M00 = c1 * c2,                M01 = -c1 * s2,               M02 = s1;
    const float M10 = c0 * s2 + s0 * s1 * c2, M11 = c0 * c2 - s0 * s1 * s2, M12 = -s0 * c1;
    const float M20 = s0 * s2 - c0 * s1 * c2, M21 = s0 * c2 + c0 * s1 * s2, M22 = c0 * c1;
    Bmat r;
    r.B00 = M00 * i00 + M01 * i01 + M02 * i02;
    r.B01 = M01 * i11 + M02 * i12;
    r.B02 = M02 * i22;
    r.B10 = M10 * i00 + M11 * i01 + M12 * i02;
    r.B11 = M11 * i11 + M12 * i12;
    r.B12 = M12 * i22;
    r.B20 = M20 * i00 + M21 * i01 + M22 * i02;
    r.B21 = M21 * i11 + M22 * i12;
    r.B22 = M22 * i22;
    return r;
}

// Compute this block's per-ray max-dot over its 256-theo chunk.
// Identical math to the harness-verified kernel; results left in mx[]/valid[].
__device__ __forceinline__ void maxdot_compute(
    const float* __restrict__ lattice, const float* __restrict__ angle,
    const float* __restrict__ uq_exp,  const int* __restrict__ hkl,
    const float* __restrict__ e_min_p,
    int n, int m, int chunk, int rg, float4* s_uq,
    float mx[RPT], bool valid[RPT])
{
    const int tid = threadIdx.x;
    const Bmat B = make_B(lattice, angle);

    // ---- stage this chunk's theo unit vectors into LDS (zeros if masked/OOB) ----
    const int ti = chunk * BLOCK + tid;
    float4 v = make_float4(0.f, 0.f, 0.f, 0.f);
    if (ti < m) {
        const float h0 = (float)hkl[3 * ti + 0];
        const float h1 = (float)hkl[3 * ti + 1];
        const float h2 = (float)hkl[3 * ti + 2];
        const float qx = B.B00 * h0 + B.B01 * h1 + B.B02 * h2;
        const float qy = B.B10 * h0 + B.B11 * h1 + B.B12 * h2;
        const float qz = B.B20 * h0 + B.B21 * h1 + B.B22 * h2;
        const float qn = sqrtf(qx * qx + qy * qy + qz * qz);
        const float inv = 1.0f / qn;
        const float ux = qx * inv, uy = qy * inv, uz = qz * inv;
        const float st = fabsf(uz);
        const float energy = HCF * qn / (2.0f * fmaxf(st, 1e-9f));
        if (energy >= e_min_p[0]) v = make_float4(ux, uy, uz, 0.f);
        // masked -> zero vector: dot = 0 -> phi = pi/2 -> exp underflows to exactly
        // 0.0f, same as reference's phi = pi contribution. Bit-identical result.
    }
    s_uq[tid] = v;
    __syncthreads();

    float rx[RPT], ry[RPT], rz[RPT];
#pragma unroll
    for (int i = 0; i < RPT; ++i) {
        const int ray = rg * RAYS_PER_BLOCK + i * BLOCK + tid;
        valid[i] = (ray < n);
        float x = 0.f, y = 0.f, z = 0.f;
        if (valid[i]) { x = uq_exp[3 * ray]; y = uq_exp[3 * ray + 1]; z = uq_exp[3 * ray + 2]; }
        rx[i] = x; ry[i] = y; rz[i] = z;
        mx[i] = 0.f;  // clamp-at-zero: negative max-dot contributes exactly 0 anyway
    }

#pragma unroll 4
    for (int j = 0; j < BLOCK; ++j) {
        const float4 t = s_uq[j];   // wave-uniform address -> LDS broadcast, no conflict
#pragma unroll
        for (int i = 0; i < RPT; ++i) {
            const float d = rx[i] * t.x + ry[i] * t.y + rz[i] * t.z;
            mx[i] = fmaxf(mx[i], d);
        }
    }
}

// ---- 2-dispatch path: per-(chunk,ray) partials via PLAIN STORES into d_ws ----
// No workspace init needed (every slot we read is written first this launch).
// Block 0 thread 0 zeroes *out so finalize's atomicAdd has a clean target.
__global__ __launch_bounds__(BLOCK) void refiner_maxdot_part_kernel(
    const float* __restrict__ lattice, const float* __restrict__ angle,
    const float* __restrict__ uq_exp,  const int* __restrict__ hkl,
    const float* __restrict__ e_min_p,
    float* __restrict__ part, float* __restrict__ out,
    int n, int m, int nchunks)
{
    __shared__ float4 s_uq[BLOCK];
    const int chunk = blockIdx.x % nchunks;
    const int rg    = blockIdx.x / nchunks;

    if (blockIdx.x == 0 && threadIdx.x == 0) *out = 0.f;

    float mx[RPT];
    bool valid[RPT];
    maxdot_compute(lattice, angle, uq_exp, hkl, e_min_p, n, m, chunk, rg, s_uq, mx, valid);

#pragma unroll
    for (int i = 0; i < RPT; ++i) {
        if (valid[i]) {
            const int ray = rg * RAYS_PER_BLOCK + i * BLOCK + threadIdx.x;
            part[(size_t)chunk * n + ray] = mx[i];   // coalesced across tid
        }
    }
}

// Finalize: per ray, max over nchunks partials (coalesced, L2-resident ~1 MB),
// then phi = acos(clip(max)), w = exp(-0.5 (phi/phi_max)^2), mean via atomics.
__global__ __launch_bounds__(BLOCK) void refiner_finalize_part_kernel(
    const float* __restrict__ part, const float* __restrict__ phi_max_p,
    float* __restrict__ out, int n, int nchunks)
{
    const int i = blockIdx.x * BLOCK + threadIdx.x;
    float w = 0.f;
    if (i < n) {
        float c = 0.f;
        for (int ch = 0; ch < nchunks; ++ch)
            c = fmaxf(c, part[(size_t)ch * n + i]);
        c = fminf(c, 1.0f - 1e-6f);           // reference's upper clip
        const float phi = acosf(c);
        const float t = phi / phi_max_p[0];
        w = expf(-0.5f * t * t);
    }
    // wave (64) reduce
#pragma unroll
    for (int off = 32; off > 0; off >>= 1) w += __shfl_down(w, off, 64);
    __shared__ float s[BLOCK / 64];
    const int lane = threadIdx.x & 63, wv = threadIdx.x >> 6;
    if (lane == 0) s[wv] = w;
    __syncthreads();
    if (threadIdx.x == 0) {
        float tot = 0.f;
#pragma unroll
        for (int k = 0; k < BLOCK / 64; ++k) tot += s[k];
        atomicAdd(out, tot / (float)n);
    }
}

// ---------------- fallback: the harness-verified atomicMax path ----------------
__global__ __launch_bounds__(BLOCK) void refiner_maxdot_kernel(
    const float* __restrict__ lattice, const float* __restrict__ angle,
    const float* __restrict__ uq_exp,  const int* __restrict__ hkl,
    const float* __restrict__ e_min_p,
    unsigned* __restrict__ maxenc, int n, int m, int nchunks)
{
    __shared__ float4 s_uq[BLOCK];
    const int chunk = blockIdx.x % nchunks;
    const int rg    = blockIdx.x / nchunks;
    float mx[RPT];
    bool valid[RPT];
    maxdot_compute(lattice, angle, uq_exp, hkl, e_min_p, n, m, chunk, rg, s_uq, mx, valid);
#pragma unroll
    for (int i = 0; i < RPT; ++i) {
        if (valid[i]) {
            const int ray = rg * RAYS_PER_BLOCK + i * BLOCK + threadIdx.x;
            // mx >= 0 so float ordering == uint ordering on the bit pattern
            atomicMax(&maxenc[ray], __float_as_uint(mx[i]));
        }
    }
}

__global__ __launch_bounds__(BLOCK) void refiner_finalize_kernel(
    const unsigned* __restrict__ maxenc, const float* __restrict__ phi_max_p,
    float* __restrict__ out, int n)
{
    const int i = blockIdx.x * BLOCK + threadIdx.x;
    float w = 0.f;
    if (i < n) {
        float c = __uint_as_float(maxenc[i]);
        c = fminf(c, 1.0f - 1e-6f);
        const float phi = acosf(c);
        const float t = phi / phi_max_p[0];
        w = expf(-0.5f * t * t);
    }
#pragma unroll
    for (int off = 32; off > 0; off >>= 1) w += __shfl_down(w, off, 64);
    __shared__ float s[BLOCK / 64];
    const int lane = threadIdx.x & 63, wv = threadIdx.x >> 6;
    if (lane == 0) s[wv] = w;
    __syncthreads();
    if (threadIdx.x == 0) {
        float tot = 0.f;
#pragma unroll
        for (int k = 0; k < BLOCK / 64; ++k) tot += s[k];
        atomicAdd(out, tot / (float)n);
    }
}

extern "C" void kernel_launch(void* const* d_in, const int* in_sizes, int n_in,
                              void* d_out, int out_size, void* d_ws, size_t ws_size,
                              hipStream_t stream) {
    const float* lattice = (const float*)d_in[0];
    const float* angle   = (const float*)d_in[1];
    const float* uq_exp  = (const float*)d_in[2];
    const int*   hkl     = (const int*)d_in[3];
    const float* phi_max = (const float*)d_in[4];
    const float* e_min   = (const float*)d_in[5];
    const int n = in_sizes[2] / 3;   // ~5000 exp rays
    const int m = in_sizes[3] / 3;   // ~12.7k hkl

    const int nchunks = (m + BLOCK - 1) / BLOCK;
    const int nrg     = (n + RAYS_PER_BLOCK - 1) / RAYS_PER_BLOCK;
    const int nblocks = nrg * nchunks;
    const int fblocks = (n + BLOCK - 1) / BLOCK;
    float* outp = (float*)d_out;

    const size_t part_bytes = (size_t)nchunks * (size_t)n * sizeof(float);
    if (part_bytes <= ws_size) {
        // 2 dispatches, zero init traffic: partials via plain stores, out zeroed in-kernel.
        float* part = (float*)d_ws;
        refiner_maxdot_part_kernel<<<dim3(nblocks), dim3(BLOCK), 0, stream>>>(
            lattice, angle, uq_exp, hkl, e_min, part, outp, n, m, nchunks);
        refiner_finalize_part_kernel<<<dim3(fblocks), dim3(BLOCK), 0, stream>>>(
            part, phi_max, outp, n, nchunks);
        return;
    }

    // fallback: verified atomicMax path (needs zeroed maxenc)
    unsigned* maxenc = (unsigned*)d_ws;
    hipMemsetAsync(maxenc, 0, (size_t)n * sizeof(unsigned), stream);
    hipMemsetAsync(d_out, 0, sizeof(float), stream);
    refiner_maxdot_kernel<<<dim3(nblocks), dim3(BLOCK), 0, stream>>>(
        lattice, angle, uq_exp, hkl, e_min, maxenc, n, m, nchunks);
    refiner_finalize_kernel<<<dim3(fblocks), dim3(BLOCK), 0, stream>>>(
        maxenc, phi_max, outp, n);
}

// Round 4
// 81.713 us; speedup vs baseline: 1.8556x; 1.1485x over previous
//
#include <hip/hip_runtime.h>
#include <math.h>

// Planck*c in J*m (f32 — matches jnp f32 reference math)
#define HCF 1.98644586e-25f

constexpr int BLOCK = 256;
constexpr int RPT   = 4;                 // rays per thread
constexpr int RAYS_PER_BLOCK = BLOCK * RPT;  // 1024

// Main kernel: each block = (ray-group rg) x (theo chunk).
// Stages one 256-entry chunk of unit theo vectors (energy-filtered) in LDS,
// each thread tracks max-dot for RPT rays, then uint-atomicMax into ws.
// Block 0 thread 0 also zeroes *out (stream-ordered before finalize's atomicAdd),
// which replaces the separate 4-byte memset dispatch.
__global__ __launch_bounds__(BLOCK) void refiner_maxdot_kernel(
    const float* __restrict__ lattice, const float* __restrict__ angle,
    const float* __restrict__ uq_exp,  const int* __restrict__ hkl,
    const float* __restrict__ e_min_p,
    unsigned* __restrict__ maxenc, float* __restrict__ out,
    int n, int m, int nchunks)
{
    __shared__ float4 s_uq[BLOCK];
    const int tid   = threadIdx.x;
    const int chunk = blockIdx.x % nchunks;
    const int rg    = blockIdx.x / nchunks;

    if (blockIdx.x == 0 && tid == 0) *out = 0.f;   // replaces d_out memset

    // ---- B_lab = rot(angle) @ inv(prim(lattice))^T, f32, redundant per thread ----
    const float a = lattice[0], b = lattice[1], cc = lattice[2];
    const float cal = cosf(lattice[3]), cbe = cosf(lattice[4]);
    const float cga = cosf(lattice[5]), sga = sinf(lattice[5]);
    const float e3y = (cal - cbe * cga) / sga;
    const float e3z = sqrtf(fmaxf(1.0f - cbe * cbe - e3y * e3y, 1e-12f));
    // prim (upper triangular)
    const float p01 = b * cga, p02 = cc * cbe, p11 = b * sga, p12 = cc * e3y, p22 = cc * e3z;
    // analytic inverse of upper-triangular prim; recip = inv(prim)^T (lower tri)
    const float i00 = 1.0f / a, i11 = 1.0f / p11, i22 = 1.0f / p22;
    const float i01 = -p01 * (i00 * i11);                       // recip[1][0]
    const float i12 = -p12 * (i11 * i22);                       // recip[2][1]
    const float i02 = (p01 * p12 - p02 * p11) * (i00 * i11 * i22); // recip[2][0]
    // rot = Rx(t0) @ Ry(t1) @ Rz(t2)
    const float c0 = cosf(angle[0]), s0 = sinf(angle[0]);
    const float c1 = cosf(angle[1]), s1 = sinf(angle[1]);
    const float c2 = cosf(angle[2]), s2 = sinf(angle[2]);
    const float M00 = c1 * c2,               M01 = -c1 * s2,              M02 = s1;
    const float M10 = c0 * s2 + s0 * s1 * c2, M11 = c0 * c2 - s0 * s1 * s2, M12 = -s0 * c1;
    const float M20 = s0 * s2 - c0 * s1 * c2, M21 = s0 * c2 + c0 * s1 * s2, M22 = c0 * c1;
    // B = M @ recip  (recip rows: [i00,0,0],[i01,i11,0],[i02,i12,i22])
    const float B00 = M00 * i00 + M01 * i01 + M02 * i02;
    const float B01 = M01 * i11 + M02 * i12;
    const float B02 = M02 * i22;
    const float B10 = M10 * i00 + M11 * i01 + M12 * i02;
    const float B11 = M11 * i11 + M12 * i12;
    const float B12 = M12 * i22;
    const float B20 = M20 * i00 + M21 * i01 + M22 * i02;
    const float B21 = M21 * i11 + M22 * i12;
    const float B22 = M22 * i22;

    // ---- stage this chunk's theo unit vectors into LDS (zeros if masked/OOB) ----
    const int ti = chunk * BLOCK + tid;
    float4 v = make_float4(0.f, 0.f, 0.f, 0.f);
    if (ti < m) {
        const float h0 = (float)hkl[3 * ti + 0];
        const float h1 = (float)hkl[3 * ti + 1];
        const float h2 = (float)hkl[3 * ti + 2];
        const float qx = B00 * h0 + B01 * h1 + B02 * h2;
        const float qy = B10 * h0 + B11 * h1 + B12 * h2;
        const float qz = B20 * h0 + B21 * h1 + B22 * h2;
        const float qn = sqrtf(qx * qx + qy * qy + qz * qz);
        const float inv = 1.0f / qn;
        const float ux = qx * inv, uy = qy * inv, uz = qz * inv;
        const float st = fabsf(uz);
        const float energy = HCF * qn / (2.0f * fmaxf(st, 1e-9f));
        if (energy >= e_min_p[0]) v = make_float4(ux, uy, uz, 0.f);
        // masked -> zero vector: dot = 0 -> phi = pi/2 -> exp underflows to exactly
        // 0.0f, same as reference's phi = pi contribution. Bit-identical result.
    }
    s_uq[tid] = v;
    __syncthreads();

    // ---- per-thread rays ----
    float rx[RPT], ry[RPT], rz[RPT], mx[RPT];
    bool valid[RPT];
#pragma unroll
    for (int i = 0; i < RPT; ++i) {
        const int ray = rg * RAYS_PER_BLOCK + i * BLOCK + tid;
        valid[i] = (ray < n);
        float x = 0.f, y = 0.f, z = 0.f;
        if (valid[i]) { x = uq_exp[3 * ray]; y = uq_exp[3 * ray + 1]; z = uq_exp[3 * ray + 2]; }
        rx[i] = x; ry[i] = y; rz[i] = z;
        mx[i] = 0.f;  // clamp-at-zero: negative max-dot contributes exactly 0 anyway
    }

#pragma unroll 4
    for (int j = 0; j < BLOCK; ++j) {
        const float4 t = s_uq[j];   // wave-uniform address -> LDS broadcast, no conflict
#pragma unroll
        for (int i = 0; i < RPT; ++i) {
            const float d = rx[i] * t.x + ry[i] * t.y + rz[i] * t.z;
            mx[i] = fmaxf(mx[i], d);
        }
    }

#pragma unroll
    for (int i = 0; i < RPT; ++i) {
        if (valid[i]) {
            const int ray = rg * RAYS_PER_BLOCK + i * BLOCK + tid;
            // mx >= 0 so float ordering == uint ordering on the bit pattern
            atomicMax(&maxenc[ray], __float_as_uint(mx[i]));
        }
    }
}

// Finalize: phi = acos(clip(max)), w = exp(-0.5 (phi/phi_max)^2), mean via atomics.
__global__ __launch_bounds__(BLOCK) void refiner_finalize_kernel(
    const unsigned* __restrict__ maxenc, const float* __restrict__ phi_max_p,
    float* __restrict__ out, int n)
{
    const int i = blockIdx.x * BLOCK + threadIdx.x;
    float w = 0.f;
    if (i < n) {
        float c = __uint_as_float(maxenc[i]);
        c = fminf(c, 1.0f - 1e-6f);           // reference's upper clip
        const float phi = acosf(c);
        const float t = phi / phi_max_p[0];
        w = expf(-0.5f * t * t);
    }
    // wave (64) reduce
#pragma unroll
    for (int off = 32; off > 0; off >>= 1) w += __shfl_down(w, off, 64);
    __shared__ float s[BLOCK / 64];
    const int lane = threadIdx.x & 63, wv = threadIdx.x >> 6;
    if (lane == 0) s[wv] = w;
    __syncthreads();
    if (threadIdx.x == 0) {
        float tot = 0.f;
#pragma unroll
        for (int k = 0; k < BLOCK / 64; ++k) tot += s[k];
        atomicAdd(out, tot / (float)n);
    }
}

extern "C" void kernel_launch(void* const* d_in, const int* in_sizes, int n_in,
                              void* d_out, int out_size, void* d_ws, size_t ws_size,
                              hipStream_t stream) {
    const float* lattice = (const float*)d_in[0];
    const float* angle   = (const float*)d_in[1];
    const float* uq_exp  = (const float*)d_in[2];
    const int*   hkl     = (const int*)d_in[3];
    const float* phi_max = (const float*)d_in[4];
    const float* e_min   = (const float*)d_in[5];
    const int n = in_sizes[2] / 3;   // ~5000 exp rays
    const int m = in_sizes[3] / 3;   // ~12.7k hkl

    unsigned* maxenc = (unsigned*)d_ws;

    // maxenc must be zeroed (atomicMax over poisoned ws would be wrong);
    // d_out zeroing is folded into the maxdot kernel (block 0).
    hipMemsetAsync(maxenc, 0, (size_t)n * sizeof(unsigned), stream);

    const int nchunks = (m + BLOCK - 1) / BLOCK;
    const int nrg     = (n + RAYS_PER_BLOCK - 1) / RAYS_PER_BLOCK;
    refiner_maxdot_kernel<<<dim3(nrg * nchunks), dim3(BLOCK), 0, stream>>>(
        lattice, angle, uq_exp, hkl, e_min, maxenc, (float*)d_out, n, m, nchunks);
    refiner_finalize_kernel<<<dim3((n + BLOCK - 1) / BLOCK), dim3(BLOCK), 0, stream>>>(
        maxenc, phi_max, (float*)d_out, n);
}